// Round 1
// baseline (494.777 us; speedup 1.0000x reference)
//
#include <hip/hip_runtime.h>

// Problem constants
#define BB 2048
#define TT 3
#define VV 62
#define FF 5
#define HH 64

// Output layout (flat, return order): x_residual[2048*62*64], Sloss, dloss, S[2048*62*62]
#define XR_OFF 0
#define SL_OFF 8126464
#define DL_OFF 8126465
#define S_OFF  8126466

#define ALPHA_F 1e-4f
#define INV_SQRT310 0.05679618342470648f  // 1/sqrt(62*5)
#define INV_SQRT15  0.2581988897471611f   // 1/sqrt(3*5)

// Prep: transpose tw (o,c,t) -> twt (t,c,o) in workspace, zero the two loss accumulators.
__global__ void prep_kernel(const float* __restrict__ tw, float* __restrict__ twt,
                            float* __restrict__ out) {
    int i = blockIdx.x * 256 + threadIdx.x;
    if (i < 12288) {
        int t = i >> 12, r = i & 4095, c = r >> 6, o = r & 63;
        twt[i] = tw[o * 192 + c * 3 + t];
    }
    if (i < 2) out[SL_OFF + i] = 0.f;
}

__launch_bounds__(256, 2)
__global__ void stgcn_kernel(
    const float* __restrict__ x,     const float* __restrict__ U1,
    const float* __restrict__ U2,    const float* __restrict__ U3,
    const float* __restrict__ be,    const float* __restrict__ Ve,
    const float* __restrict__ W1,    const float* __restrict__ W2,
    const float* __restrict__ W3,    const float* __restrict__ bs,
    const float* __restrict__ Vs,    const float* __restrict__ a,
    const float* __restrict__ Theta, const float* __restrict__ twt,
    const float* __restrict__ tb,    const float* __restrict__ rw,
    const float* __restrict__ rb,    const float* __restrict__ gamma_,
    const float* __restrict__ beta_, float* __restrict__ out)
{
    __shared__ float sx[930];    // x[b]  [t][v][f]
    __shared__ float sxT[930];   // x_TAt [u][v][f]
    __shared__ float sS[3844];   // tmpS -> S -> C1 = S*At          [u][v] (stride 62)
    __shared__ float sAt[3844];  // Sm -> spatial_At -> C2=(2S^2-I)*At
    __shared__ float sP[3968];   // sigmoid(s_prod+bs) [62][62] ; later gcn_t [v][64]
    __shared__ float sG[992];    // z2 scratch; later G_t [v][16] (kf=15)
    __shared__ float sTh[960];   // Theta [kf][o]
    __shared__ float sDiag[62];  // diag of spatial_At
    __shared__ float sL[186];    // temporal lhs [t][u62]; later s_lhs [v][3]
    __shared__ float sR[186];    // temporal rhs [v][t3];  later s_rhs [t][v62]
    __shared__ float sy[15], sprod[9], sE[9], stAt[9];
    __shared__ float scol[62];   // 1/colsum of tmpS
    __shared__ float sred[16];   // reductions: [0..3] Sloss waves, [8..12] dloss per f

    const int b   = blockIdx.x;
    const int tid = threadIdx.x;
    const int o   = tid & 63;
    const int q   = tid >> 6;            // wave id; uniform within wave
    const int nv  = (q < 2) ? 16 : 15;   // #valid v = q + 4j

    // ---- stage A: loads ----
    for (int i = tid; i < 930; i += 256) sx[i] = x[b * 930 + i];
    for (int i = tid; i < 960; i += 256) sTh[i] = Theta[i];
    float rw5[5];
    #pragma unroll
    for (int f = 0; f < 5; ++f) rw5[f] = rw[o * 5 + f];
    const float rb_o = rb[o], tb_o = tb[o], gam = gamma_[o], bet = beta_[o];
    __syncthreads();

    // ---- stage B: temporal attention ----
    // y[t][f] = sum_v x[t][v][f]*U1[v]
    if (tid < 15) {
        int t = tid / 5, f = tid % 5;
        float s = 0.f;
        for (int v = 0; v < 62; ++v) s += sx[t * 310 + v * 5 + f] * U1[v];
        sy[tid] = s;
    }
    // rhs[v][t] = sum_f U3[f]*x[t][v][f]
    if (tid < 186) {
        int v = tid / 3, t = tid % 3;
        float s = 0.f;
        for (int f = 0; f < 5; ++f) s += U3[f] * sx[t * 310 + v * 5 + f];
        sR[v * 3 + t] = s;
    }
    __syncthreads();
    // lhs[t][u] = sum_f y[t][f]*U2[f][u]
    if (tid < 186) {
        int t = tid / 62, u = tid % 62;
        float s = 0.f;
        for (int f = 0; f < 5; ++f) s += sy[t * 5 + f] * U2[f * 62 + u];
        sL[t * 62 + u] = s;
    }
    __syncthreads();
    // prod[t][u] = sum_v lhs[t][v]*rhs[v][u]
    if (tid < 9) {
        int t = tid / 3, u = tid % 3;
        float s = 0.f;
        for (int v = 0; v < 62; ++v) s += sL[t * 62 + v] * sR[v * 3 + u];
        sprod[tid] = s;
    }
    __syncthreads();
    // E[t][u] = sum_s Ve[t][s]*sigmoid(prod[s][u]+be[s][u])
    if (tid < 9) {
        int t = tid / 3, u = tid % 3;
        float s = 0.f;
        for (int ss = 0; ss < 3; ++ss) {
            float p  = sprod[ss * 3 + u] + be[ss * 3 + u];
            float sg = 1.f / (1.f + __expf(-p));
            s += Ve[t * 3 + ss] * sg;
        }
        sE[tid] = s;
    }
    __syncthreads();
    // temporal softmax over t per u
    if (tid < 3) {
        int u = tid;
        float m = -1e30f;
        for (int t = 0; t < 3; ++t) m = fmaxf(m, sE[t * 3 + u]);
        float e0 = __expf(sE[0 * 3 + u] - m);
        float e1 = __expf(sE[1 * 3 + u] - m);
        float e2 = __expf(sE[2 * 3 + u] - m);
        float inv = 1.f / (e0 + e1 + e2);
        stAt[0 * 3 + u] = e0 * inv;
        stAt[1 * 3 + u] = e1 * inv;
        stAt[2 * 3 + u] = e2 * inv;
    }
    __syncthreads();
    // x_TAt[u][v][f] = sum_t x[t][v][f]*At[t][u] / sqrt(310)
    for (int i = tid; i < 930; i += 256) {
        int u = i / 310, r = i % 310;
        float s = 0.f;
        for (int t = 0; t < 3; ++t) s += sx[t * 310 + r] * stAt[t * 3 + u];
        sxT[i] = s * INV_SQRT310;
    }
    __syncthreads();

    // ---- stage C: spatial attention ----
    // z2[v][f] = sum_u xT[u][v][f]*W1[u]  (into sG scratch)
    for (int i = tid; i < 310; i += 256) {
        float s = 0.f;
        for (int t = 0; t < 3; ++t) s += sxT[t * 310 + i] * W1[t];
        sG[i] = s;
    }
    // s_rhs[t][v] = sum_f W3[f]*xT[t][v][f]
    if (tid < 186) {
        int t = tid / 62, v = tid % 62;
        float s = 0.f;
        for (int f = 0; f < 5; ++f) s += W3[f] * sxT[t * 310 + v * 5 + f];
        sR[t * 62 + v] = s;
    }
    __syncthreads();
    // s_lhs[v][s] = sum_f z2[v][f]*W2[f][s]
    if (tid < 186) {
        int v = tid / 3, s3 = tid % 3;
        float s = 0.f;
        for (int f = 0; f < 5; ++f) s += sG[v * 5 + f] * W2[f * 3 + s3];
        sL[v * 3 + s3] = s;
    }
    __syncthreads();
    // sig[u][v] = sigmoid(sum_t s_lhs[u][t]*s_rhs[t][v] + bs[u][v])
    for (int i = tid; i < 3844; i += 256) {
        int u = i / 62, v = i - u * 62;
        float s = bs[i];
        for (int t = 0; t < 3; ++t) s += sL[u * 3 + t] * sR[t * 62 + v];
        sP[i] = 1.f / (1.f + __expf(-s));
    }
    __syncthreads();
    // Sm[u][v] = sum_w Vs[u][w]*sig[w][v]
    for (int i = tid; i < 3844; i += 256) {
        int u = i / 62, v = i - u * 62;
        const float* vr = Vs + u * 62;
        float s = 0.f;
        for (int w = 0; w < 62; ++w) s += vr[w] * sP[w * 62 + v];
        sAt[i] = s;
    }
    __syncthreads();
    // spatial softmax over u (columns)
    if (tid < 62) {
        int v = tid;
        float m = -1e30f;
        for (int u = 0; u < 62; ++u) m = fmaxf(m, sAt[u * 62 + v]);
        float den = 0.f;
        for (int u = 0; u < 62; ++u) {
            float e = __expf(sAt[u * 62 + v] - m);
            sAt[u * 62 + v] = e;
            den += e;
        }
        float inv = 1.f / den;
        for (int u = 0; u < 62; ++u) sAt[u * 62 + v] *= inv;
    }

    // ---- stage D: S matrix, losses ----
    // tmpS[i][j] = exp(relu(sum_f |xm[i][f]-xm[j][f]|*a[f])), xm = x[:,1]
    for (int idx = tid; idx < 3844; idx += 256) {
        int i = idx / 62, j = idx - i * 62;
        float s = 0.f;
        #pragma unroll
        for (int f = 0; f < 5; ++f)
            s += fabsf(sx[310 + i * 5 + f] - sx[310 + j * 5 + f]) * a[f];
        sS[idx] = __expf(fmaxf(s, 0.f));
    }
    __syncthreads();
    if (tid < 62) {
        int j = tid;
        float s = 0.f;
        for (int i = 0; i < 62; ++i) s += sS[i * 62 + j];
        scol[j] = 1.f / s;
    }
    // dloss partial: sum_{j,f} d2 = sum_f (2*62*sum(xm^2) - 2*(sum xm)^2)
    if (tid < 5) {
        float su = 0.f, sq = 0.f;
        for (int v = 0; v < 62; ++v) {
            float xv = sx[310 + v * 5 + tid];
            su += xv; sq += xv * xv;
        }
        sred[8 + tid] = 124.f * sq - 2.f * su * su;
    }
    __syncthreads();
    // normalize S, write out, Sloss partial; fuse C1/C2 transform
    float slp = 0.f;
    for (int idx = tid; idx < 3844; idx += 256) {
        int i = idx / 62, j = idx - i * 62;
        float sv = sS[idx] * scol[j];
        out[S_OFF + (size_t)b * 3844 + idx] = sv;
        slp += sv * sv;
        float A = sAt[idx];
        if (i == j) sDiag[i] = A;
        sS[idx] = sv * A;                               // C1 = S*At
        float c2 = 2.f * sv * sv; if (i == j) c2 -= 1.f;
        sAt[idx] = c2 * A;                              // C2 = (2S^2 - I)*At
    }
    // Sloss reduce
    for (int m = 32; m > 0; m >>= 1) slp += __shfl_down(slp, m, 64);
    if ((tid & 63) == 0) sred[q] = slp;
    __syncthreads();
    if (tid == 0) {
        atomicAdd(out + SL_OFF, (sred[0] + sred[1] + sred[2] + sred[3]) * (ALPHA_F / 2048.f));
        float dl = sred[8] + sred[9] + sred[10] + sred[11] + sred[12];
        atomicAdd(out + DL_OFF, dl * ALPHA_F);
    }

    // ---- stage F: spatial GCN + temporal conv, accumulate tc in regs ----
    float acc[16];
    #pragma unroll
    for (int j = 0; j < 16; ++j) acc[j] = 0.f;

    for (int t = 0; t < 3; ++t) {
        __syncthreads();
        // step1: G_t[v][kf]  (kf = k*5+f, k in {0,1,2})
        for (int i = tid; i < 310; i += 256) {
            int v = i / 5, f = i - v * 5;
            float g0 = sDiag[v] * sx[t * 310 + i];
            float g1 = 0.f, g2 = 0.f;
            for (int u = 0; u < 62; ++u) {
                float xa = sx[t * 310 + u * 5 + f];
                g1 -= sS[u * 62 + v] * xa;   // cheb1 = -S
                g2 += sAt[u * 62 + v] * xa;  // cheb2 = 2S^2 - I
            }
            sG[v * 16 + f]      = g0;
            sG[v * 16 + 5 + f]  = g1;
            sG[v * 16 + 10 + f] = g2;
        }
        __syncthreads();
        // step2: gcn_t[v][o] = relu(sum_kf G[v][kf]*Theta[kf][o])
        #pragma unroll
        for (int j = 0; j < 16; ++j) {
            if (j < nv) {
                int v = q + 4 * j;
                float s = 0.f;
                #pragma unroll
                for (int kf = 0; kf < 15; ++kf) s += sG[v * 16 + kf] * sTh[kf * 64 + o];
                sP[v * 64 + o] = fmaxf(s, 0.f);
            }
        }
        __syncthreads();
        // step3: tc[o][v] += sum_c gcn_t[v][c]*tw[o][c][t]
        const float* twtp = twt + t * 4096;
        for (int c = 0; c < 64; ++c) {
            float w = twtp[c * 64 + o];   // coalesced, L1-hot
            #pragma unroll
            for (int j = 0; j < 16; ++j) {
                if (j < nv) acc[j] += sP[(q + 4 * j) * 64 + c] * w;  // LDS broadcast
            }
        }
    }

    // ---- epilogue: res + tc, relu, LayerNorm over o (64 lanes of wave) ----
    #pragma unroll
    for (int j = 0; j < 16; ++j) {
        if (j < nv) {
            int v = q + 4 * j;
            float r = rb_o;
            #pragma unroll
            for (int f = 0; f < 5; ++f) r += sx[v * 5 + f] * rw5[f];  // x[:,0]
            float z = r + (acc[j] + tb_o) * INV_SQRT15;
            z = fmaxf(z, 0.f);
            float s1 = z, s2 = z * z;
            #pragma unroll
            for (int m = 1; m < 64; m <<= 1) {
                s1 += __shfl_xor(s1, m, 64);
                s2 += __shfl_xor(s2, m, 64);
            }
            float mean = s1 * 0.015625f;
            float var  = s2 * 0.015625f - mean * mean;
            float ov   = (z - mean) * rsqrtf(var + 1e-5f) * gam + bet;
            out[XR_OFF + (size_t)b * 3968 + v * 64 + o] = ov;
        }
    }
}

extern "C" void kernel_launch(void* const* d_in, const int* in_sizes, int n_in,
                              void* d_out, int out_size, void* d_ws, size_t ws_size,
                              hipStream_t stream) {
    const float* x   = (const float*)d_in[0];
    const float* U1  = (const float*)d_in[1];
    const float* U2  = (const float*)d_in[2];
    const float* U3  = (const float*)d_in[3];
    const float* be  = (const float*)d_in[4];
    const float* Ve  = (const float*)d_in[5];
    const float* W1  = (const float*)d_in[6];
    const float* W2  = (const float*)d_in[7];
    const float* W3  = (const float*)d_in[8];
    const float* bs  = (const float*)d_in[9];
    const float* Vs  = (const float*)d_in[10];
    const float* a   = (const float*)d_in[11];
    const float* Th  = (const float*)d_in[12];
    const float* tw  = (const float*)d_in[13];
    const float* tb  = (const float*)d_in[14];
    const float* rw  = (const float*)d_in[15];
    const float* rb  = (const float*)d_in[16];
    const float* gm  = (const float*)d_in[17];
    const float* bt  = (const float*)d_in[18];
    float* out = (float*)d_out;
    float* twt = (float*)d_ws;  // 12288 floats

    prep_kernel<<<48, 256, 0, stream>>>(tw, twt, out);
    stgcn_kernel<<<2048, 256, 0, stream>>>(x, U1, U2, U3, be, Ve, W1, W2, W3,
                                           bs, Vs, a, Th, twt, tb, rw, rb, gm, bt, out);
}